// Round 1
// baseline (450.500 us; speedup 1.0000x reference)
//
#include <hip/hip_runtime.h>
#include <hip/hip_bf16.h>
#include <stdint.h>

#define B 32
#define S 8192
#define D 256
#define H 256
#define LDA 264  // padded LDS row stride in shorts (264*2=528B, 528/4=132 dwords; 132%32=4 -> conflict-minimal)

typedef __attribute__((ext_vector_type(8))) short bf16x8;
typedef __attribute__((ext_vector_type(4))) float f32x4;

__device__ inline unsigned short f2bf(float f) {
  // round-to-nearest-even fp32 -> bf16
  unsigned u = __float_as_uint(f);
  unsigned r = (u + 0x7FFFu + ((u >> 16) & 1u)) >> 16;
  return (unsigned short)r;
}

__device__ inline float fast_tanh(float x) {
  // tanh(x) = 1 - 2/(1+e^{2x}); v_exp based, ~6 VALU ops
  float e = __expf(2.0f * x);
  return 1.0f - 2.0f * __builtin_amdgcn_rcpf(1.0f + e);
}

// ---------------------------------------------------------------------------
// Prep: blocks 0..63 swizzle W_e into MFMA-B fragment-sequential bf16;
//       blocks 64..95 run the LSTM cell + dec_proj (one block per batch).
// ---------------------------------------------------------------------------
__global__ __launch_bounds__(1024) void prep_kernel(
    const float* __restrict__ h0, const float* __restrict__ c0,
    const float* __restrict__ start_token, const float* __restrict__ W_k,
    const float* __restrict__ W_r, const float* __restrict__ b_lstm,
    const float* __restrict__ W_e, const float* __restrict__ W_d,
    const float* __restrict__ b_d,
    unsigned short* __restrict__ Wfrag, float* __restrict__ dec) {
  int blk = blockIdx.x;
  int tid = threadIdx.x;

  __shared__ float xs[D], hs[H], zs[4 * H], hv[H], dpp[4][H];

  if (blk < 64) {
    // Fragment-sequential layout: idx = (((nt*8 + kt)*64 + lane)*8 + j)
    // lane holds B[k][n], n = nt*16 + (lane&15), k = kt*32 + (lane>>4)*8 + j
    int gid = blk * 1024 + tid;  // 0..65535
    int j = gid & 7;
    int lane = (gid >> 3) & 63;
    int kt = (gid >> 9) & 7;
    int nt = gid >> 12;
    int n = nt * 16 + (lane & 15);
    int k = kt * 32 + (lane >> 4) * 8 + j;
    Wfrag[gid] = f2bf(W_e[k * H + n]);
  } else {
    int b = blk - 64;
    if (tid < D) xs[tid] = start_token[b * D + tid];
    else if (tid < 2 * D) hs[tid - D] = h0[b * H + (tid - D)];
    __syncthreads();
    {
      int jj = tid;  // 0..1023: one gate-column each
      float a0 = 0.f, a1 = 0.f, a2 = 0.f, a3 = 0.f;
      #pragma unroll 8
      for (int d = 0; d < D; d += 4) {
        a0 += xs[d + 0] * W_k[(d + 0) * 1024 + jj];
        a1 += xs[d + 1] * W_k[(d + 1) * 1024 + jj];
        a2 += xs[d + 2] * W_k[(d + 2) * 1024 + jj];
        a3 += xs[d + 3] * W_k[(d + 3) * 1024 + jj];
      }
      #pragma unroll 8
      for (int h = 0; h < H; h += 4) {
        a0 += hs[h + 0] * W_r[(h + 0) * 1024 + jj];
        a1 += hs[h + 1] * W_r[(h + 1) * 1024 + jj];
        a2 += hs[h + 2] * W_r[(h + 2) * 1024 + jj];
        a3 += hs[h + 3] * W_r[(h + 3) * 1024 + jj];
      }
      zs[jj] = b_lstm[jj] + ((a0 + a1) + (a2 + a3));
    }
    __syncthreads();
    if (tid < H) {
      float zi = zs[tid], zf = zs[H + tid], zg = zs[2 * H + tid], zo = zs[3 * H + tid];
      float si = 1.0f / (1.0f + expf(-zi));
      float sf = 1.0f / (1.0f + expf(-zf));
      float so = 1.0f / (1.0f + expf(-zo));
      float c = sf * c0[b * H + tid] + si * tanhf(zg);
      hv[tid] = so * tanhf(c);
    }
    __syncthreads();
    {
      int hcol = tid & (H - 1);
      int q = tid >> 8;  // 0..3 quarter of the K dim
      float a = 0.f;
      #pragma unroll 8
      for (int k = q * 64; k < q * 64 + 64; ++k) a += hv[k] * W_d[k * H + hcol];
      dpp[q][hcol] = a;
    }
    __syncthreads();
    if (tid < H)
      dec[b * H + tid] = dpp[0][tid] + dpp[1][tid] + dpp[2][tid] + dpp[3][tid] + b_d[tid];
  }
}

// ---------------------------------------------------------------------------
// Main: one block = 64 encoder rows (one batch), full N=256.
// 4 waves split N (64 cols each). bf16 MFMA 16x16x32, fp32 accumulate.
// Fused epilogue: tanh(acc + bias) * v_w, reduce over n -> scores.
// ---------------------------------------------------------------------------
__global__ __launch_bounds__(256, 2) void attn_kernel(
    const float* __restrict__ enc, const unsigned short* __restrict__ Wfrag,
    const float* __restrict__ dec, const float* __restrict__ b_e,
    const float* __restrict__ v_w, float* __restrict__ scores) {
  __shared__ unsigned short Ash[64 * LDA];
  __shared__ float bias_sh[H], vw_sh[H], part_sh[4][64];

  int tid = threadIdx.x;
  int b = blockIdx.x >> 7;        // 128 tiles per batch
  int st = blockIdx.x & 127;
  long row0 = (long)b * S + st * 64;
  const float* Abase = enc + row0 * (long)D;

  bias_sh[tid] = b_e[tid] + dec[b * H + tid];
  vw_sh[tid] = v_w[tid];

  // Stage A tile (64 x 256 fp32) -> bf16 LDS. Per instr: 16 rows x 64B, coalesced.
  {
    int r = tid >> 2;
    int c4 = (tid & 3) * 4;
    const float* src = Abase + r * D;
    unsigned short* dst = Ash + r * LDA;
    #pragma unroll
    for (int jj = 0; jj < 16; ++jj) {
      int c = c4 + jj * 16;
      float4 v = *(const float4*)(src + c);
      ushort4 o;
      o.x = f2bf(v.x); o.y = f2bf(v.y); o.z = f2bf(v.z); o.w = f2bf(v.w);
      *(ushort4*)(dst + c) = o;
    }
  }
  __syncthreads();

  int wave = tid >> 6, lane = tid & 63;
  int ml = lane & 15, kg = lane >> 4;

  f32x4 acc[4][4];
  #pragma unroll
  for (int i = 0; i < 4; ++i)
    #pragma unroll
    for (int q = 0; q < 4; ++q) acc[i][q] = (f32x4){0.f, 0.f, 0.f, 0.f};

  #pragma unroll
  for (int kt = 0; kt < 8; ++kt) {
    bf16x8 wfr[4], afr[4];
    #pragma unroll
    for (int q = 0; q < 4; ++q) {
      int nt = wave * 4 + q;
      const unsigned short* p = Wfrag + (((nt * 8 + kt) * 64 + lane) << 3);
      wfr[q] = *(const bf16x8*)p;  // 1KB/instr fully coalesced, L2-hot
    }
    #pragma unroll
    for (int i = 0; i < 4; ++i) {
      const unsigned short* p = Ash + (i * 16 + ml) * LDA + kt * 32 + kg * 8;
      afr[i] = *(const bf16x8*)p;  // ds_read_b128, conflict-minimal
    }
    #pragma unroll
    for (int i = 0; i < 4; ++i)
      #pragma unroll
      for (int q = 0; q < 4; ++q)
        acc[i][q] = __builtin_amdgcn_mfma_f32_16x16x32_bf16(afr[i], wfr[q], acc[i][q], 0, 0, 0);
  }

  // Epilogue: t = tanh(acc + bias[n]); partial[m] += t * v_w[n]
  float part[16];
  #pragma unroll
  for (int v = 0; v < 16; ++v) part[v] = 0.f;
  #pragma unroll
  for (int q = 0; q < 4; ++q) {
    int n = wave * 64 + q * 16 + ml;  // C layout: col = lane&15
    float bs = bias_sh[n], vw = vw_sh[n];
    #pragma unroll
    for (int i = 0; i < 4; ++i)
      #pragma unroll
      for (int r = 0; r < 4; ++r) {
        float t = fast_tanh(acc[i][q][r] + bs);
        part[i * 4 + r] += t * vw;
      }
  }
  // reduce over the 16 column-lanes (lane&15)
  #pragma unroll
  for (int m = 1; m < 16; m <<= 1)
    #pragma unroll
    for (int v = 0; v < 16; ++v) part[v] += __shfl_xor(part[v], m, 64);
  if (ml == 0) {
    #pragma unroll
    for (int i = 0; i < 4; ++i)
      #pragma unroll
      for (int r = 0; r < 4; ++r)
        part_sh[wave][i * 16 + kg * 4 + r] = part[i * 4 + r];  // row = (lane>>4)*4 + reg
  }
  __syncthreads();
  if (tid < 64) {
    float s = part_sh[0][tid] + part_sh[1][tid] + part_sh[2][tid] + part_sh[3][tid];
    scores[row0 + tid] = s;  // v_b dropped: softmax is shift-invariant
  }
}

// ---------------------------------------------------------------------------
// Softmax over each row of (B, S)
// ---------------------------------------------------------------------------
__global__ __launch_bounds__(1024) void softmax_kernel(
    const float* __restrict__ scores, float* __restrict__ out) {
  int b = blockIdx.x;
  int tid = threadIdx.x;
  __shared__ float red[16];
  const float* src = scores + (long)b * S;
  float v[8];
  float lmax = -1e30f;
  #pragma unroll
  for (int j = 0; j < 8; ++j) {
    v[j] = src[tid + j * 1024];
    lmax = fmaxf(lmax, v[j]);
  }
  #pragma unroll
  for (int m = 1; m < 64; m <<= 1) lmax = fmaxf(lmax, __shfl_xor(lmax, m, 64));
  if ((tid & 63) == 0) red[tid >> 6] = lmax;
  __syncthreads();
  float M = red[0];
  #pragma unroll
  for (int i = 1; i < 16; ++i) M = fmaxf(M, red[i]);
  __syncthreads();
  float ls = 0.f;
  #pragma unroll
  for (int j = 0; j < 8; ++j) {
    v[j] = __expf(v[j] - M);
    ls += v[j];
  }
  #pragma unroll
  for (int m = 1; m < 64; m <<= 1) ls += __shfl_xor(ls, m, 64);
  if ((tid & 63) == 0) red[tid >> 6] = ls;
  __syncthreads();
  float total = 0.f;
  #pragma unroll
  for (int i = 0; i < 16; ++i) total += red[i];
  float inv = __builtin_amdgcn_rcpf(total);
  #pragma unroll
  for (int j = 0; j < 8; ++j) out[(long)b * S + tid + j * 1024] = v[j] * inv;
}

extern "C" void kernel_launch(void* const* d_in, const int* in_sizes, int n_in,
                              void* d_out, int out_size, void* d_ws, size_t ws_size,
                              hipStream_t stream) {
  const float* enc         = (const float*)d_in[0];
  const float* h0          = (const float*)d_in[1];
  const float* c0          = (const float*)d_in[2];
  const float* start_token = (const float*)d_in[3];
  const float* W_k         = (const float*)d_in[4];
  const float* W_r         = (const float*)d_in[5];
  const float* b_lstm      = (const float*)d_in[6];
  const float* W_e         = (const float*)d_in[7];
  const float* b_e         = (const float*)d_in[8];
  const float* W_d         = (const float*)d_in[9];
  const float* b_d         = (const float*)d_in[10];
  const float* v_w         = (const float*)d_in[11];
  // d_in[12] = v_b: softmax(s + c) == softmax(s), so it cancels exactly.
  float* out = (float*)d_out;

  char* wsb = (char*)d_ws;
  float* scores         = (float*)wsb;                                   // B*S*4   = 1 MB
  unsigned short* Wfrag = (unsigned short*)(wsb + (size_t)B * S * 4);    // D*H*2   = 128 KB
  float* dec            = (float*)(wsb + (size_t)B * S * 4 + (size_t)D * H * 2);  // B*H*4 = 32 KB

  prep_kernel<<<96, 1024, 0, stream>>>(h0, c0, start_token, W_k, W_r, b_lstm,
                                       W_e, W_d, b_d, Wfrag, dec);
  attn_kernel<<<B * (S / 64), 256, 0, stream>>>(enc, Wfrag, dec, b_e, v_w, scores);
  softmax_kernel<<<B, 1024, 0, stream>>>(scores, out);
}